// Round 9
// baseline (143.021 us; speedup 1.0000x reference)
//
#include <hip/hip_runtime.h>

#define HID 1024
#define RANK 16
#define NSEG 64
#define G 16               // tokens per tile (one chain amortizes A+B over 16 tokens)
#define NXCD 8

// ws layout (ints): base[64] | cursor[64] | desc[gtiles] | sorted[gtiles*16]
// desc: (s<<19) | (cnt<<14) | start   (start<16384, cnt<=16, s<64); -1 = unused

__global__ __launch_bounds__(1024) void k_hist_scan(
    const int* __restrict__ seg, int N,
    int* __restrict__ base_g, int* __restrict__ cursor_g,
    int* __restrict__ desc_g, int gtiles)
{
    __shared__ int hist[NSEG];
    __shared__ int ltot;
    const int tid = threadIdx.x;
    if (tid < NSEG) hist[tid] = 0;
    __syncthreads();
    for (int i = tid; i < N; i += 1024) atomicAdd(&hist[seg[i]], 1);
    __syncthreads();

    if (tid < 64) {                       // wave 0 only
        const int h = hist[tid];
        const int p = (h + 15) & ~15;     // padded to 16
        int v = p;                        // inclusive scan of padded counts
        #pragma unroll
        for (int off = 1; off < 64; off <<= 1) {
            int u = __shfl_up(v, off, 64);
            if (tid >= off) v += u;
        }
        const int b = v - p;              // exclusive padded base
        base_g[tid]   = b;
        cursor_g[tid] = 0;
        if (tid == 63) ltot = v;
        const int nt = (h + 15) >> 4;
        for (int k = 0; k < nt; ++k) {
            const int cnt = min(16, h - (k << 4));
            desc_g[(b >> 4) + k] = (tid << 19) | (cnt << 14) | (b + (k << 4));
        }
    }
    __syncthreads();
    const int totTiles = ltot >> 4;
    for (int t = totTiles + tid; t < gtiles; t += 1024) desc_g[t] = -1;
}

__global__ __launch_bounds__(256) void k_scatter(
    const int* __restrict__ seg, int N,
    const int* __restrict__ base_g, int* __restrict__ cursor_g,
    int* __restrict__ sorted)
{
    const int i = blockIdx.x * 256 + threadIdx.x;
    if (i < N) {
        const int s = seg[i];
        const int pos = atomicAdd(&cursor_g[s], 1);
        sorted[base_g[s] + pos] = i;
    }
}

__global__ __launch_bounds__(256) void k_apply(
    const float* __restrict__ x,       // [N, H]
    const int*   __restrict__ sorted,
    const int*   __restrict__ desc,
    const float* __restrict__ A,       // [S, H, R]
    const float* __restrict__ B,       // [S, R, H]
    const float* __restrict__ bias,    // [S, H]
    float*       __restrict__ out,     // [N, H]
    int chunkPerXcd)
{
    const int work = (blockIdx.x & (NXCD - 1)) * chunkPerXcd + (blockIdx.x >> 3);
    const int d = desc[work];
    if (d < 0) return;
    const int s     = d >> 19;
    const int cnt   = (d >> 14) & 31;
    const int start = d & 16383;

    const int tid  = threadIdx.x;
    const int lane = tid & 63;
    const int w    = tid >> 6;

    __shared__ float4 x_lds[G][HID / 4];       // [16][256] float4 = 64 KB
    __shared__ float  red[4][16][68];          // wave transpose-reduce pad
    __shared__ float  inter_lds[G][RANK];      // 1 KB

    const int n0 = sorted[start];

    // ---- stage x: wave w stages rows j = w*4..w*4+3 (coalesced 1KB/instr) ----
    #pragma unroll
    for (int jj = 0; jj < 4; ++jj) {
        const int j  = w * 4 + jj;
        const int nj = (j < cnt) ? sorted[start + j] : n0;
        const float4* xr = (const float4*)(x + (size_t)nj * HID);
        #pragma unroll
        for (int k = 0; k < 4; ++k)
            x_lds[j][k * 64 + lane] = xr[k * 64 + lane];
    }

    // token ids for the store phase (static indexing only)
    int n[G];
    #pragma unroll
    for (int j = 0; j < G; ++j)
        n[j] = (j < cnt) ? sorted[start + j] : n0;

    __syncthreads();                           // x staged

    // ---- phase 1: inter[j][r] = sum_h B[s][r][h] * x[j][h] ----
    // wave owns r = w*4+rr; all 16 tokens from LDS
    const float4* B4 = (const float4*)(B + (size_t)s * RANK * HID);
    float acc[4][G];
    #pragma unroll
    for (int rr = 0; rr < 4; ++rr)
        #pragma unroll
        for (int j = 0; j < G; ++j) acc[rr][j] = 0.f;

    #pragma unroll
    for (int k = 0; k < 4; ++k) {
        float4 b[4];
        #pragma unroll
        for (int rr = 0; rr < 4; ++rr)
            b[rr] = B4[(size_t)(w * 4 + rr) * (HID / 4) + k * 64 + lane];
        #pragma unroll
        for (int j = 0; j < G; ++j) {
            const float4 xj = x_lds[j][k * 64 + lane];
            #pragma unroll
            for (int rr = 0; rr < 4; ++rr)
                acc[rr][j] += b[rr].x * xj.x + b[rr].y * xj.y
                            + b[rr].z * xj.z + b[rr].w * xj.w;
        }
    }

    // ---- wave-local transpose-reduce, 4 passes of 16 values ----
    const int v = lane & 15;
    const int q = lane >> 4;
    #pragma unroll
    for (int p = 0; p < 4; ++p) {
        #pragma unroll
        for (int idx = 0; idx < 16; ++idx)
            red[w][idx][lane] = acc[idx >> 2][p * 4 + (idx & 3)];
        const float4* rp = (const float4*)&red[w][v][q * 16];
        float4 r0 = rp[0], r1 = rp[1], r2 = rp[2], r3 = rp[3];
        float sum = ((r0.x + r0.y) + (r0.z + r0.w))
                  + ((r1.x + r1.y) + (r1.z + r1.w))
                  + ((r2.x + r2.y) + (r2.z + r2.w))
                  + ((r3.x + r3.y) + (r3.z + r3.w));
        sum += __shfl_xor(sum, 16, 64);
        sum += __shfl_xor(sum, 32, 64);
        if (lane < 16)                          // idx v = rr*4+jj
            inter_lds[p * 4 + (v & 3)][w * 4 + (v >> 2)] = sum;
    }
    __syncthreads();                            // inter ready

    // ---- phase 2: out[n[j]][h] = A[s][h][:]·inter[j] + bias[s][h] ----
    const float4* A4 = (const float4*)(A + (size_t)s * HID * RANK);
    float4 av[4][4];
    #pragma unroll
    for (int jh = 0; jh < 4; ++jh)
        #pragma unroll
        for (int qq = 0; qq < 4; ++qq)
            av[jh][qq] = A4[(size_t)(tid * 4 + jh) * (RANK / 4) + qq];
    const float4 bia = ((const float4*)(bias + (size_t)s * HID))[tid];

    #pragma unroll
    for (int j = 0; j < G; ++j) {
        const float4* I4 = (const float4*)inter_lds[j];
        float4 iv[4];
        #pragma unroll
        for (int qq = 0; qq < 4; ++qq) iv[qq] = I4[qq];
        float4 o = bia;
        float* op = (float*)&o;
        #pragma unroll
        for (int jh = 0; jh < 4; ++jh) {
            float a = 0.f;
            #pragma unroll
            for (int qq = 0; qq < 4; ++qq)
                a += av[jh][qq].x * iv[qq].x + av[jh][qq].y * iv[qq].y
                   + av[jh][qq].z * iv[qq].z + av[jh][qq].w * iv[qq].w;
            op[jh] += a;
        }
        if (j < cnt)
            ((float4*)(out + (size_t)n[j] * HID))[tid] = o;
    }
}

extern "C" void kernel_launch(void* const* d_in, const int* in_sizes, int n_in,
                              void* d_out, int out_size, void* d_ws, size_t ws_size,
                              hipStream_t stream) {
    const float* x    = (const float*)d_in[0];
    const int*   seg  = (const int*)d_in[1];
    const float* A    = (const float*)d_in[2];
    const float* B    = (const float*)d_in[3];
    const float* bias = (const float*)d_in[4];
    float* out = (float*)d_out;

    const int N = in_sizes[1];
    const int gtiles = (((N + G - 1) / G) + NSEG + 7) & ~7;   // 576 for N=8192

    int* wsi    = (int*)d_ws;
    int* base_g = wsi;
    int* cursor = wsi + NSEG;
    int* desc   = wsi + 2 * NSEG;
    int* sorted = wsi + 2 * NSEG + gtiles;

    k_hist_scan<<<1, 1024, 0, stream>>>(seg, N, base_g, cursor, desc, gtiles);
    k_scatter  <<<(N + 255) / 256, 256, 0, stream>>>(seg, N, base_g, cursor, sorted);
    k_apply    <<<gtiles, 256, 0, stream>>>(x, sorted, desc, A, B, bias, out,
                                            gtiles / NXCD);
}

// Round 10
// 131.127 us; speedup vs baseline: 1.0907x; 1.0907x over previous
//
#include <hip/hip_runtime.h>

#define HID 1024
#define RANK 16
#define NSEG 64
#define T 32               // tokens per tile
#define KC 4               // K-chunks of 256 in k_inter
#define NXCD 8

// ws ints: base[64] | cursor[64] | desc[gtiles] | sorted[gtiles*T] | part[gtiles*KC*T*RANK] (floats)
// desc: (s<<20) | (cnt<<14) | start ; -1 = unused

__global__ __launch_bounds__(1024) void k_hist_scan(
    const int* __restrict__ seg, int N,
    int* __restrict__ base_g, int* __restrict__ cursor_g,
    int* __restrict__ desc_g, int gtiles)
{
    __shared__ int hist[NSEG];
    __shared__ int ltot;
    const int tid = threadIdx.x;
    if (tid < NSEG) hist[tid] = 0;
    __syncthreads();
    for (int i = tid; i < N; i += 1024) atomicAdd(&hist[seg[i]], 1);
    __syncthreads();

    if (tid < 64) {
        const int h = hist[tid];
        const int p = (h + T - 1) & ~(T - 1);      // padded to 32
        int v = p;
        #pragma unroll
        for (int off = 1; off < 64; off <<= 1) {
            int u = __shfl_up(v, off, 64);
            if (tid >= off) v += u;
        }
        const int b = v - p;                        // exclusive padded base
        base_g[tid]   = b;
        cursor_g[tid] = 0;
        if (tid == 63) ltot = v;
        const int nt = (h + T - 1) >> 5;
        for (int k = 0; k < nt; ++k) {
            const int cnt = min(T, h - (k << 5));
            desc_g[(b >> 5) + k] = (tid << 20) | (cnt << 14) | (b + (k << 5));
        }
    }
    __syncthreads();
    for (int t = (ltot >> 5) + tid; t < gtiles; t += 1024) desc_g[t] = -1;
}

__global__ __launch_bounds__(256) void k_scatter(
    const int* __restrict__ seg, int N,
    const int* __restrict__ base_g, int* __restrict__ cursor_g,
    int* __restrict__ sorted)
{
    const int i = blockIdx.x * 256 + threadIdx.x;
    if (i < N) {
        const int s = seg[i];
        const int pos = atomicAdd(&cursor_g[s], 1);
        sorted[base_g[s] + pos] = i;
    }
}

// grid = gtiles*KC ; block computes partial inter for (tile, kchunk):
// part[tile][c][tok][r] = sum_{h in c*256..+255} B[s][r][h] * x[n_tok][h]
__global__ __launch_bounds__(256) void k_inter(
    const float* __restrict__ x,
    const int*   __restrict__ sorted,
    const int*   __restrict__ desc,
    const float* __restrict__ B,
    float*       __restrict__ part,
    int chunkPerXcd)
{
    const int bid  = blockIdx.x;
    const int work = (bid & (NXCD - 1)) * chunkPerXcd + (bid >> 3);
    const int tile = work >> 2;
    const int c    = work & 3;
    const int d = desc[tile];
    if (d < 0) return;
    const int s     = d >> 20;
    const int cnt   = (d >> 14) & 63;
    const int start = d & 16383;

    const int tid  = threadIdx.x;
    const int lane = tid & 63;
    const int w    = tid >> 6;

    __shared__ float red[4][16][68];     // per-wave transpose-reduce pad (17.4 KB)

    // wave-shared B rows for this k-chunk: 16 coalesced 1KB loads.
    // All 4 waves read the same 16KB -> 3/4 are L1 hits; no LDS staging needed.
    const float4* B4 = (const float4*)B + (size_t)s * (RANK * HID / 4);
    float4 br[16];
    #pragma unroll
    for (int r = 0; r < 16; ++r)
        br[r] = B4[r * (HID / 4) + c * 64 + lane];

    const int n0 = sorted[start];
    const int v  = lane & 15;
    const int q  = lane >> 4;
    float* outp = part + ((size_t)tile * KC + c) * (T * RANK);

    // wave w owns tokens w*8 .. w*8+7
    #pragma unroll
    for (int j = 0; j < 8; ++j) {
        const int tok = w * 8 + j;
        const int nj  = (tok < cnt) ? sorted[start + tok] : n0;
        const float4 xv = ((const float4*)x)[(size_t)nj * (HID / 4) + c * 64 + lane];

        float acc[16];
        #pragma unroll
        for (int r = 0; r < 16; ++r)
            acc[r] = br[r].x * xv.x + br[r].y * xv.y + br[r].z * xv.z + br[r].w * xv.w;

        // wave-local transpose-reduce (LDS pipe in-order per wave; no barrier)
        #pragma unroll
        for (int r = 0; r < 16; ++r) red[w][r][lane] = acc[r];
        const float4* rp = (const float4*)&red[w][v][q * 16];
        float4 r0 = rp[0], r1 = rp[1], r2 = rp[2], r3 = rp[3];
        float sum = ((r0.x + r0.y) + (r0.z + r0.w))
                  + ((r1.x + r1.y) + (r1.z + r1.w))
                  + ((r2.x + r2.y) + (r2.z + r2.w))
                  + ((r3.x + r3.y) + (r3.z + r3.w));
        sum += __shfl_xor(sum, 16, 64);
        sum += __shfl_xor(sum, 32, 64);
        if (lane < 16) outp[tok * RANK + v] = sum;   // lane v holds r=v
    }
}

// grid = gtiles*4 ; block computes out[tile tokens][hc*256..+255]
__global__ __launch_bounds__(256) void k_out(
    const int*   __restrict__ sorted,
    const int*   __restrict__ desc,
    const float* __restrict__ A,
    const float* __restrict__ bias,
    const float* __restrict__ part,
    float*       __restrict__ out,
    int chunkPerXcd)
{
    const int bid  = blockIdx.x;
    const int work = (bid & (NXCD - 1)) * chunkPerXcd + (bid >> 3);
    const int tile = work >> 2;
    const int hc   = work & 3;
    const int d = desc[tile];
    if (d < 0) return;
    const int s     = d >> 20;
    const int cnt   = (d >> 14) & 63;
    const int start = d & 16383;

    const int tid = threadIdx.x;

    __shared__ float2 inter2[T * RANK / 2];   // [32][16] floats = 2 KB
    __shared__ int    tok_lds[T];

    if (tid < T) tok_lds[tid] = (tid < cnt) ? sorted[start + tid] : -1;

    // inter[tok][r] = sum over 4 k-chunk partials (coalesced float2 loads)
    {
        const float2* p2 = (const float2*)(part + (size_t)tile * KC * (T * RANK));
        float2 a0 = p2[tid], a1 = p2[256 + tid], a2 = p2[512 + tid], a3 = p2[768 + tid];
        inter2[tid] = make_float2(a0.x + a1.x + a2.x + a3.x,
                                  a0.y + a1.y + a2.y + a3.y);
    }

    // A row for this thread's h (16 KB per block through L1, once)
    const float4* A4 = (const float4*)A + (size_t)s * (HID * RANK / 4);
    float4 av[4];
    #pragma unroll
    for (int qq = 0; qq < 4; ++qq)
        av[qq] = A4[(size_t)(hc * 256 + tid) * (RANK / 4) + qq];
    const float bi = bias[(size_t)s * HID + hc * 256 + tid];

    __syncthreads();

    const float* il = (const float*)inter2;
    #pragma unroll 8
    for (int j = 0; j < T; ++j) {
        const int nj = tok_lds[j];
        const float4* iv = (const float4*)&il[j * RANK];   // broadcast reads
        float4 i0 = iv[0], i1 = iv[1], i2 = iv[2], i3 = iv[3];
        float o = bi
            + av[0].x * i0.x + av[0].y * i0.y + av[0].z * i0.z + av[0].w * i0.w
            + av[1].x * i1.x + av[1].y * i1.y + av[1].z * i1.z + av[1].w * i1.w
            + av[2].x * i2.x + av[2].y * i2.y + av[2].z * i2.z + av[2].w * i2.w
            + av[3].x * i3.x + av[3].y * i3.y + av[3].z * i3.z + av[3].w * i3.w;
        if (nj >= 0)
            out[(size_t)nj * HID + hc * 256 + tid] = o;
    }
}

extern "C" void kernel_launch(void* const* d_in, const int* in_sizes, int n_in,
                              void* d_out, int out_size, void* d_ws, size_t ws_size,
                              hipStream_t stream) {
    const float* x    = (const float*)d_in[0];
    const int*   seg  = (const int*)d_in[1];
    const float* A    = (const float*)d_in[2];
    const float* B    = (const float*)d_in[3];
    const float* bias = (const float*)d_in[4];
    float* out = (float*)d_out;

    const int N = in_sizes[1];
    const int gtiles = (((N + T - 1) / T) + NSEG + 7) & ~7;   // 320 for N=8192

    int* wsi    = (int*)d_ws;
    int* base_g = wsi;
    int* cursor = wsi + NSEG;
    int* desc   = wsi + 2 * NSEG;
    int* sorted = wsi + 2 * NSEG + gtiles;
    float* part = (float*)(wsi + 2 * NSEG + gtiles + gtiles * T);

    const int grid = gtiles * 4;              // multiple of 32
    k_hist_scan<<<1, 1024, 0, stream>>>(seg, N, base_g, cursor, desc, gtiles);
    k_scatter  <<<(N + 255) / 256, 256, 0, stream>>>(seg, N, base_g, cursor, sorted);
    k_inter    <<<grid, 256, 0, stream>>>(x, sorted, desc, B, part, grid / NXCD);
    k_out      <<<grid, 256, 0, stream>>>(sorted, desc, A, bias, part, out, grid / NXCD);
}